// Round 1
// baseline (939.608 us; speedup 1.0000x reference)
//
#include <hip/hip_runtime.h>

#define D 64
#define H 64
#define EFD 16
#define KF 145
#define FS 148   // f tile row stride (floats), 16B-aligned
#define MS 68    // m/y1 tile row stride
#define TE 128   // edges per block
#define TN 128   // nodes per block
#define ZS 132   // z tile row stride (K=128 + pad)

__device__ __forceinline__ float silu(float x) {
    return x / (1.0f + __expf(-x));
}

// acc[j] += sum_kk a[kk] * b[kk][j], b stored as float4 bf[4] (bp[kk*4+j])
#define GEMM_STEP(acc_, a_, bf_) do { \
    const float* bp_ = (const float*)(bf_); \
    acc_[0] += (a_).x*bp_[0] + (a_).y*bp_[4] + (a_).z*bp_[8]  + (a_).w*bp_[12]; \
    acc_[1] += (a_).x*bp_[1] + (a_).y*bp_[5] + (a_).z*bp_[9]  + (a_).w*bp_[13]; \
    acc_[2] += (a_).x*bp_[2] + (a_).y*bp_[6] + (a_).z*bp_[10] + (a_).w*bp_[14]; \
    acc_[3] += (a_).x*bp_[3] + (a_).y*bp_[7] + (a_).z*bp_[11] + (a_).w*bp_[15]; \
} while (0)

__global__ __launch_bounds__(256, 2) void edge_kernel(
    const float* __restrict__ node_feat,
    const float* __restrict__ coord,
    const float* __restrict__ edge_feat,
    const int* __restrict__ src,
    const int* __restrict__ dst,
    const float* __restrict__ W_e1, const float* __restrict__ b_e1,
    const float* __restrict__ W_e2, const float* __restrict__ b_e2,
    float* __restrict__ h_neigh,
    int E)
{
    __shared__ float smem[TE * FS];   // f tile [TE][FS]; later reused as m tile [TE][MS]
    __shared__ int sidx[2 * TE];      // src | dst

    const int tid = threadIdx.x;
    const int ebase = blockIdx.x * TE;

    if (tid < TE) {
        int e = ebase + tid;
        int s = 0, d2 = 0;
        if (e < E) { s = src[e]; d2 = dst[e]; }
        sidx[tid] = s;
        sidx[TE + tid] = d2;
    }
    __syncthreads();

    // ---- stage f = [h_src(64) | h_dst(64) | radial(1) | edge_feat(16)] ----
    {
        const int k = tid & 63, eo = tid >> 6;
        for (int e = eo; e < TE; e += 4) {
            int s = sidx[e], d2 = sidx[TE + e];
            smem[e * FS + k]      = node_feat[(size_t)s * D + k];
            smem[e * FS + 64 + k] = node_feat[(size_t)d2 * D + k];
        }
        const int k2 = tid & 15, e2 = tid >> 4;
        for (int e = e2; e < TE; e += 16) {
            int ge = ebase + e;
            smem[e * FS + 129 + k2] = (ge < E) ? edge_feat[(size_t)ge * EFD + k2] : 0.f;
        }
        if (tid < TE) {
            int s = sidx[tid], d2 = sidx[TE + tid];
            float dx = coord[s*3+0] - coord[d2*3+0];
            float dy = coord[s*3+1] - coord[d2*3+1];
            float dz = coord[s*3+2] - coord[d2*3+2];
            smem[tid * FS + 128] = dx*dx + dy*dy + dz*dz;
        }
    }
    __syncthreads();

    const int eg = tid >> 4;   // 0..15 -> 8 edges each
    const int hg = tid & 15;   // 0..15 -> 4 outs each

    // ---- MLP1: [TE,145] @ W_e1[145,64] + b, silu ----
    float acc[8][4];
    {
        float4 b0 = *(const float4*)&b_e1[4*hg];
        #pragma unroll
        for (int i = 0; i < 8; i++) {
            acc[i][0]=b0.x; acc[i][1]=b0.y; acc[i][2]=b0.z; acc[i][3]=b0.w;
        }
    }
    for (int k4 = 0; k4 < 36; k4++) {
        float4 bf[4];
        #pragma unroll
        for (int kk = 0; kk < 4; kk++)
            bf[kk] = *(const float4*)&W_e1[(size_t)(4*k4+kk) * H + 4*hg];
        #pragma unroll
        for (int i = 0; i < 8; i++) {
            float4 a = *(const float4*)&smem[(8*eg + i) * FS + 4*k4];
            GEMM_STEP(acc[i], a, bf);
        }
    }
    {   // tail k = 144
        float4 b = *(const float4*)&W_e1[(size_t)144 * H + 4*hg];
        #pragma unroll
        for (int i = 0; i < 8; i++) {
            float a = smem[(8*eg+i)*FS + 144];
            acc[i][0] += a*b.x; acc[i][1] += a*b.y; acc[i][2] += a*b.z; acc[i][3] += a*b.w;
        }
    }
    __syncthreads();   // all f reads done before overwrite

    // write m = silu(acc) into smem as [TE][MS]
    #pragma unroll
    for (int i = 0; i < 8; i++) {
        float4 mv;
        mv.x = silu(acc[i][0]); mv.y = silu(acc[i][1]);
        mv.z = silu(acc[i][2]); mv.w = silu(acc[i][3]);
        *(float4*)&smem[(8*eg+i)*MS + 4*hg] = mv;
    }
    __syncthreads();

    // ---- MLP2: [TE,64] @ W_e2[64,64] + b, silu, scatter ----
    float acc2[8][4];
    {
        float4 b0 = *(const float4*)&b_e2[4*hg];
        #pragma unroll
        for (int i = 0; i < 8; i++) {
            acc2[i][0]=b0.x; acc2[i][1]=b0.y; acc2[i][2]=b0.z; acc2[i][3]=b0.w;
        }
    }
    for (int k4 = 0; k4 < 16; k4++) {
        float4 bf[4];
        #pragma unroll
        for (int kk = 0; kk < 4; kk++)
            bf[kk] = *(const float4*)&W_e2[(size_t)(4*k4+kk) * H + 4*hg];
        #pragma unroll
        for (int i = 0; i < 8; i++) {
            float4 a = *(const float4*)&smem[(8*eg + i) * MS + 4*k4];
            GEMM_STEP(acc2[i], a, bf);
        }
    }
    const int emax = E - ebase;
    #pragma unroll
    for (int i = 0; i < 8; i++) {
        int e = 8*eg + i;
        if (e < emax) {
            float* hp = &h_neigh[(size_t)sidx[TE + e] * H + 4*hg];
            atomicAdd(&hp[0], silu(acc2[i][0]));
            atomicAdd(&hp[1], silu(acc2[i][1]));
            atomicAdd(&hp[2], silu(acc2[i][2]));
            atomicAdd(&hp[3], silu(acc2[i][3]));
        }
    }
}

__global__ __launch_bounds__(256, 2) void node_kernel(
    const float* __restrict__ node_feat,
    const float* __restrict__ h_neigh,
    const float* __restrict__ W_n1, const float* __restrict__ b_n1,
    const float* __restrict__ W_n2, const float* __restrict__ b_n2,
    float* __restrict__ out, int N)
{
    __shared__ float smem[TN * ZS];  // z tile [TN][ZS]; reused as y1 [TN][MS]

    const int tid = threadIdx.x;
    const int nbase = blockIdx.x * TN;

    {
        const int k = tid & 63, no = tid >> 6;
        for (int n = no; n < TN; n += 4) {
            int gn = nbase + n;
            int cg = (gn < N) ? gn : (N - 1);
            smem[n*ZS + k]      = node_feat[(size_t)cg * D + k];
            smem[n*ZS + 64 + k] = h_neigh[(size_t)cg * D + k];
        }
    }
    __syncthreads();

    const int ng = tid >> 4;
    const int hg = tid & 15;

    float acc[8][4];
    {
        float4 b0 = *(const float4*)&b_n1[4*hg];
        #pragma unroll
        for (int i = 0; i < 8; i++) {
            acc[i][0]=b0.x; acc[i][1]=b0.y; acc[i][2]=b0.z; acc[i][3]=b0.w;
        }
    }
    for (int k4 = 0; k4 < 32; k4++) {
        float4 bf[4];
        #pragma unroll
        for (int kk = 0; kk < 4; kk++)
            bf[kk] = *(const float4*)&W_n1[(size_t)(4*k4+kk) * H + 4*hg];
        #pragma unroll
        for (int i = 0; i < 8; i++) {
            float4 a = *(const float4*)&smem[(8*ng + i) * ZS + 4*k4];
            GEMM_STEP(acc[i], a, bf);
        }
    }
    __syncthreads();

    #pragma unroll
    for (int i = 0; i < 8; i++) {
        float4 mv;
        mv.x = silu(acc[i][0]); mv.y = silu(acc[i][1]);
        mv.z = silu(acc[i][2]); mv.w = silu(acc[i][3]);
        *(float4*)&smem[(8*ng+i)*MS + 4*hg] = mv;
    }
    __syncthreads();

    float acc2[8][4];
    {
        float4 b0 = *(const float4*)&b_n2[4*hg];
        #pragma unroll
        for (int i = 0; i < 8; i++) {
            acc2[i][0]=b0.x; acc2[i][1]=b0.y; acc2[i][2]=b0.z; acc2[i][3]=b0.w;
        }
    }
    for (int k4 = 0; k4 < 16; k4++) {
        float4 bf[4];
        #pragma unroll
        for (int kk = 0; kk < 4; kk++)
            bf[kk] = *(const float4*)&W_n2[(size_t)(4*k4+kk) * H + 4*hg];
        #pragma unroll
        for (int i = 0; i < 8; i++) {
            float4 a = *(const float4*)&smem[(8*ng + i) * MS + 4*k4];
            GEMM_STEP(acc2[i], a, bf);
        }
    }

    #pragma unroll
    for (int i = 0; i < 8; i++) {
        int gn = nbase + 8*ng + i;
        if (gn < N) {
            float4 ov;
            ov.x = acc2[i][0]; ov.y = acc2[i][1]; ov.z = acc2[i][2]; ov.w = acc2[i][3];
            *(float4*)&out[(size_t)gn * D + 4*hg] = ov;
        }
    }
}

extern "C" void kernel_launch(void* const* d_in, const int* in_sizes, int n_in,
                              void* d_out, int out_size, void* d_ws, size_t ws_size,
                              hipStream_t stream)
{
    const float* node_feat = (const float*)d_in[0];
    const float* coord     = (const float*)d_in[1];
    const float* edge_feat = (const float*)d_in[2];
    const int*   src       = (const int*)d_in[3];
    const int*   dst       = (const int*)d_in[4];
    const float* W_e1 = (const float*)d_in[5];
    const float* b_e1 = (const float*)d_in[6];
    const float* W_e2 = (const float*)d_in[7];
    const float* b_e2 = (const float*)d_in[8];
    const float* W_n1 = (const float*)d_in[9];
    const float* b_n1 = (const float*)d_in[10];
    const float* W_n2 = (const float*)d_in[11];
    const float* b_n2 = (const float*)d_in[12];

    const int N = in_sizes[0] / D;
    const int E = in_sizes[3];

    float* h_neigh = (float*)d_ws;
    hipMemsetAsync(h_neigh, 0, (size_t)N * H * sizeof(float), stream);

    const int eblocks = (E + TE - 1) / TE;
    edge_kernel<<<eblocks, 256, 0, stream>>>(node_feat, coord, edge_feat, src, dst,
                                             W_e1, b_e1, W_e2, b_e2, h_neigh, E);

    const int nblocks = (N + TN - 1) / TN;
    node_kernel<<<nblocks, 256, 0, stream>>>(node_feat, h_neigh,
                                             W_n1, b_n1, W_n2, b_n2,
                                             (float*)d_out, N);
}